// Round 1
// baseline (61.529 us; speedup 1.0000x reference)
//
#include <hip/hip_runtime.h>

#define NUM_CLASSES 26
#define NCOUNT (3 * NUM_CLASSES)

__global__ void sdl_zero_counts(unsigned int* __restrict__ c) {
    int i = threadIdx.x;
    if (i < NCOUNT) c[i] = 0u;
}

__global__ __launch_bounds__(256) void sdl_hist_kernel(
    const int* __restrict__ f, const int* __restrict__ m,
    unsigned int* __restrict__ gc, int n4) {
    __shared__ unsigned int h[NCOUNT];
    for (int i = threadIdx.x; i < NCOUNT; i += blockDim.x) h[i] = 0u;
    __syncthreads();

    const int4* __restrict__ f4 = (const int4*)f;
    const int4* __restrict__ m4 = (const int4*)m;
    int stride = gridDim.x * blockDim.x;
    for (int i = blockIdx.x * blockDim.x + threadIdx.x; i < n4; i += stride) {
        int4 a = f4[i];
        int4 b = m4[i];
        // fixed-volume histogram
        atomicAdd(&h[a.x], 1u);
        atomicAdd(&h[a.y], 1u);
        atomicAdd(&h[a.z], 1u);
        atomicAdd(&h[a.w], 1u);
        // moving-volume histogram
        atomicAdd(&h[NUM_CLASSES + b.x], 1u);
        atomicAdd(&h[NUM_CLASSES + b.y], 1u);
        atomicAdd(&h[NUM_CLASSES + b.z], 1u);
        atomicAdd(&h[NUM_CLASSES + b.w], 1u);
        // intersection histogram
        if (a.x == b.x) atomicAdd(&h[2 * NUM_CLASSES + a.x], 1u);
        if (a.y == b.y) atomicAdd(&h[2 * NUM_CLASSES + a.y], 1u);
        if (a.z == b.z) atomicAdd(&h[2 * NUM_CLASSES + a.z], 1u);
        if (a.w == b.w) atomicAdd(&h[2 * NUM_CLASSES + a.w], 1u);
    }
    __syncthreads();
    for (int i = threadIdx.x; i < NCOUNT; i += blockDim.x) {
        unsigned int v = h[i];
        if (v) atomicAdd(&gc[i], v);
    }
}

__global__ void sdl_finalize(const unsigned int* __restrict__ gc,
                             float* __restrict__ out) {
    if (threadIdx.x == 0) {
        const float eps = 1e-5f;
        float s = 0.f;
        for (int c = 1; c < NUM_CLASSES; ++c) {
            float F = (float)gc[c];
            float M = (float)gc[NUM_CLASSES + c];
            float I = (float)gc[2 * NUM_CLASSES + c];
            s += (2.f * I + eps) / (F + M + eps);
        }
        out[0] = 1.f - s / (float)(NUM_CLASSES - 1);
    }
}

extern "C" void kernel_launch(void* const* d_in, const int* in_sizes, int n_in,
                              void* d_out, int out_size, void* d_ws, size_t ws_size,
                              hipStream_t stream) {
    const int* f = (const int*)d_in[0];
    const int* m = (const int*)d_in[1];
    unsigned int* gc = (unsigned int*)d_ws;
    float* out = (float*)d_out;

    int n = in_sizes[0];          // 14,155,776 (divisible by 4)
    int n4 = n / 4;

    sdl_zero_counts<<<1, 128, 0, stream>>>(gc);

    int blocks = (n4 + 255) / 256;
    if (blocks > 2048) blocks = 2048;
    sdl_hist_kernel<<<blocks, 256, 0, stream>>>(f, m, gc, n4);

    sdl_finalize<<<1, 64, 0, stream>>>(gc, out);
}

// Round 2
// 51.731 us; speedup vs baseline: 1.1894x; 1.1894x over previous
//
#include <hip/hip_runtime.h>

#define NUM_CLASSES 26
#define SUBS 4                        // sub-histograms per class to cut same-address atomic serialization
#define NCOUNT (3 * NUM_CLASSES)      // 78 global counters
#define LDSN (NCOUNT * SUBS)          // 312 LDS counters

__global__ void sdl_zero_counts(unsigned int* __restrict__ c) {
    int i = threadIdx.x;
    if (i < NCOUNT) c[i] = 0u;
}

// F hist base = 0, M hist base = 26, I hist base = 52; LDS index = (hist*26+class)*SUBS + sub
__global__ __launch_bounds__(256) void sdl_hist8(
    const int4* __restrict__ f4, const int4* __restrict__ m4,
    unsigned int* __restrict__ gc, int n4, int nfull) {
    __shared__ unsigned int h[LDSN];
    for (int i = threadIdx.x; i < LDSN; i += 256) h[i] = 0u;
    __syncthreads();

    const int tid    = blockIdx.x * 256 + threadIdx.x;
    const int stride = gridDim.x * 256;
    const int sub    = threadIdx.x & (SUBS - 1);

    for (int base = tid; base < nfull; base += stride * 8) {
        int4 a[8], b[8];
        // issue all 16 loads back-to-back: 256 B in flight per thread
        #pragma unroll
        for (int k = 0; k < 8; ++k) a[k] = f4[base + k * stride];
        #pragma unroll
        for (int k = 0; k < 8; ++k) b[k] = m4[base + k * stride];

        #pragma unroll
        for (int k = 0; k < 8; ++k) {
            int4 aa = a[k], bb = b[k];
            atomicAdd(&h[aa.x * SUBS + sub], 1u);
            atomicAdd(&h[aa.y * SUBS + sub], 1u);
            atomicAdd(&h[aa.z * SUBS + sub], 1u);
            atomicAdd(&h[aa.w * SUBS + sub], 1u);
            atomicAdd(&h[(NUM_CLASSES + bb.x) * SUBS + sub], 1u);
            atomicAdd(&h[(NUM_CLASSES + bb.y) * SUBS + sub], 1u);
            atomicAdd(&h[(NUM_CLASSES + bb.z) * SUBS + sub], 1u);
            atomicAdd(&h[(NUM_CLASSES + bb.w) * SUBS + sub], 1u);
            if (aa.x == bb.x) atomicAdd(&h[(2 * NUM_CLASSES + aa.x) * SUBS + sub], 1u);
            if (aa.y == bb.y) atomicAdd(&h[(2 * NUM_CLASSES + aa.y) * SUBS + sub], 1u);
            if (aa.z == bb.z) atomicAdd(&h[(2 * NUM_CLASSES + aa.z) * SUBS + sub], 1u);
            if (aa.w == bb.w) atomicAdd(&h[(2 * NUM_CLASSES + aa.w) * SUBS + sub], 1u);
        }
    }
    // tail (empty when n4 % (stride*8) == 0)
    for (int i = nfull + tid; i < n4; i += stride) {
        int4 aa = f4[i], bb = m4[i];
        atomicAdd(&h[aa.x * SUBS + sub], 1u);
        atomicAdd(&h[aa.y * SUBS + sub], 1u);
        atomicAdd(&h[aa.z * SUBS + sub], 1u);
        atomicAdd(&h[aa.w * SUBS + sub], 1u);
        atomicAdd(&h[(NUM_CLASSES + bb.x) * SUBS + sub], 1u);
        atomicAdd(&h[(NUM_CLASSES + bb.y) * SUBS + sub], 1u);
        atomicAdd(&h[(NUM_CLASSES + bb.z) * SUBS + sub], 1u);
        atomicAdd(&h[(NUM_CLASSES + bb.w) * SUBS + sub], 1u);
        if (aa.x == bb.x) atomicAdd(&h[(2 * NUM_CLASSES + aa.x) * SUBS + sub], 1u);
        if (aa.y == bb.y) atomicAdd(&h[(2 * NUM_CLASSES + aa.y) * SUBS + sub], 1u);
        if (aa.z == bb.z) atomicAdd(&h[(2 * NUM_CLASSES + aa.z) * SUBS + sub], 1u);
        if (aa.w == bb.w) atomicAdd(&h[(2 * NUM_CLASSES + aa.w) * SUBS + sub], 1u);
    }

    __syncthreads();
    for (int i = threadIdx.x; i < NCOUNT; i += 256) {
        unsigned int v = h[i * SUBS] + h[i * SUBS + 1] + h[i * SUBS + 2] + h[i * SUBS + 3];
        if (v) atomicAdd(&gc[i], v);
    }
}

__global__ void sdl_finalize(const unsigned int* __restrict__ gc,
                             float* __restrict__ out) {
    if (threadIdx.x == 0) {
        const float eps = 1e-5f;
        float s = 0.f;
        for (int c = 1; c < NUM_CLASSES; ++c) {
            float F = (float)gc[c];
            float M = (float)gc[NUM_CLASSES + c];
            float I = (float)gc[2 * NUM_CLASSES + c];
            s += (2.f * I + eps) / (F + M + eps);
        }
        out[0] = 1.f - s / (float)(NUM_CLASSES - 1);
    }
}

extern "C" void kernel_launch(void* const* d_in, const int* in_sizes, int n_in,
                              void* d_out, int out_size, void* d_ws, size_t ws_size,
                              hipStream_t stream) {
    const int* f = (const int*)d_in[0];
    const int* m = (const int*)d_in[1];
    unsigned int* gc = (unsigned int*)d_ws;
    float* out = (float*)d_out;

    int n = in_sizes[0];          // 14,155,776 (divisible by 4)
    int n4 = n / 4;               // 3,538,944 int4-pairs

    sdl_zero_counts<<<1, 128, 0, stream>>>(gc);

    // choose blocks so each thread does exactly 8 int4-pairs when divisible
    int blocks = n4 / (256 * 8);
    if (blocks < 1) blocks = 1;
    if (blocks > 4096) blocks = 4096;
    int stride = blocks * 256;
    int nfull = (n4 / (stride * 8)) * (stride * 8);

    sdl_hist8<<<blocks, 256, 0, stream>>>((const int4*)f, (const int4*)m, gc, n4, nfull);

    sdl_finalize<<<1, 64, 0, stream>>>(gc, out);
}